// Round 1
// baseline (2398.164 us; speedup 1.0000x reference)
//
#include <hip/hip_runtime.h>

#define H 2048
#define I_DIM 4096
#define NE 8
#define T_TOK 2048

#define BM 128
#define BK 32
#define LDK 40   // padded LDS row stride (elements); byte stride 80 -> 16B-aligned b128 frags
#define MT 16    // max m-tiles per expert (covers worst case 2048 tokens on one expert)

typedef float f32x4 __attribute__((ext_vector_type(4)));
typedef short s16x8 __attribute__((ext_vector_type(8)));

__device__ __forceinline__ unsigned short f2bf(float f) {
  unsigned int u = __builtin_bit_cast(unsigned int, f);
  u += 0x7FFFu + ((u >> 16) & 1u);   // RNE
  return (unsigned short)(u >> 16);
}

__device__ __forceinline__ f32x4 mfma16(s16x8 a, s16x8 b, f32x4 c) {
  return __builtin_amdgcn_mfma_f32_16x16x32_bf16(a, b, c, 0, 0, 0);
}

// ---------------- K1: RMSNorm + router + top-2 + expert list build ----------------
__global__ __launch_bounds__(256) void k_norm_router(
    const float* __restrict__ x, const float* __restrict__ nw,
    const float* __restrict__ rw, unsigned short* __restrict__ tn,
    int* __restrict__ counts, int* __restrict__ tok, float* __restrict__ wgt)
{
  __shared__ float s_ssq[4];
  __shared__ float s_l[32];
  const int t = blockIdx.x, tid = threadIdx.x;
  const int wid = tid >> 6, lane = tid & 63;

  const float* xr = x + (size_t)t * H + tid * 8;
  float4 v0 = *(const float4*)xr;
  float4 v1 = *(const float4*)(xr + 4);
  float xv[8] = {v0.x, v0.y, v0.z, v0.w, v1.x, v1.y, v1.z, v1.w};

  float ssq = 0.f;
#pragma unroll
  for (int j = 0; j < 8; j++) ssq += xv[j] * xv[j];
#pragma unroll
  for (int o = 32; o > 0; o >>= 1) ssq += __shfl_down(ssq, o);
  if (lane == 0) s_ssq[wid] = ssq;
  __syncthreads();
  const float scale =
      rsqrtf((s_ssq[0] + s_ssq[1] + s_ssq[2] + s_ssq[3]) * (1.0f / H) + 1e-6f);

  const float* nwp = nw + tid * 8;
  float4 w0 = *(const float4*)nwp;
  float4 w1 = *(const float4*)(nwp + 4);
  float wv[8] = {w0.x, w0.y, w0.z, w0.w, w1.x, w1.y, w1.z, w1.w};

  float tv[8];
  union { unsigned short us[8]; uint4 v; } pk;
#pragma unroll
  for (int j = 0; j < 8; j++) {
    tv[j] = xv[j] * scale * wv[j];     // fp32 normalized value (router uses this)
    pk.us[j] = f2bf(tv[j]);            // bf16 copy for the GEMMs
  }
  *(uint4*)(tn + (size_t)t * H + tid * 8) = pk.v;

  // router partial logits (fp32; rw rows of 8 experts are contiguous)
  float l[8] = {0, 0, 0, 0, 0, 0, 0, 0};
  const float* rwp = rw + (size_t)(tid * 8) * NE;
#pragma unroll
  for (int j = 0; j < 8; j++) {
#pragma unroll
    for (int e2 = 0; e2 < 8; e2++) l[e2] += tv[j] * rwp[j * NE + e2];
  }
#pragma unroll
  for (int e2 = 0; e2 < 8; e2++) {
#pragma unroll
    for (int o = 32; o > 0; o >>= 1) l[e2] += __shfl_down(l[e2], o);
  }
  if (lane == 0) {
#pragma unroll
    for (int e2 = 0; e2 < 8; e2++) s_l[wid * 8 + e2] = l[e2];
  }
  __syncthreads();
  if (tid == 0) {
    float tot[8];
#pragma unroll
    for (int e2 = 0; e2 < 8; e2++)
      tot[e2] = s_l[e2] + s_l[8 + e2] + s_l[16 + e2] + s_l[24 + e2];
    int b0 = 0; float m0 = tot[0];
#pragma unroll
    for (int e2 = 1; e2 < 8; e2++) if (tot[e2] > m0) { m0 = tot[e2]; b0 = e2; }
    int b1 = -1; float m1 = -3.4e38f;
#pragma unroll
    for (int e2 = 0; e2 < 8; e2++)
      if (e2 != b0 && tot[e2] > m1) { m1 = tot[e2]; b1 = e2; }
    // normalized top-2 affinities == pairwise softmax of top-2 logits
    float wa = 1.0f / (1.0f + expf(m1 - m0));
    float wb = 1.0f - wa;
    int p0 = atomicAdd(&counts[b0], 1);
    tok[b0 * T_TOK + p0] = t; wgt[b0 * T_TOK + p0] = wa;
    int p1 = atomicAdd(&counts[b1], 1);
    tok[b1 * T_TOK + p1] = t; wgt[b1 * T_TOK + p1] = wb;
  }
}

// ---------------- K2: grouped GEMM gate+up, silu(g)*u -> hbuf (bf16) ----------------
// grid = NE * MT * (I_DIM/64), mt fastest so same-(e,nt) blocks share B via L2
__global__ __launch_bounds__(256) void k_gate_up(
    const unsigned short* __restrict__ tn,
    const float* __restrict__ wg, const float* __restrict__ wu,
    const int* __restrict__ counts, const int* __restrict__ tok,
    unsigned short* __restrict__ hbuf)
{
  __shared__ unsigned short At[BM * LDK];
  __shared__ unsigned short Btg[64 * LDK];
  __shared__ unsigned short Btu[64 * LDK];

  const int bid = blockIdx.x;
  const int e = bid / (MT * (I_DIM / 64));
  const int rem = bid % (MT * (I_DIM / 64));
  const int nt = rem >> 4;   // 0..63
  const int mt = rem & 15;
  const int cnt = counts[e];
  if (mt * BM >= cnt) return;
  int off = 0;
#pragma unroll
  for (int i = 0; i < NE; i++) off += (i < e) ? counts[i] : 0;

  const int tid = threadIdx.x;
  // A staging roles: row = tid>>2 (+64), 8 bf16 chunk = tid&3
  const int ar = tid >> 2, aq = tid & 3;
  const int m0 = mt * BM + ar, m1 = m0 + 64;
  const int t0 = tok[e * T_TOK + ((m0 < cnt) ? m0 : (cnt - 1))];
  const int t1 = tok[e * T_TOK + ((m1 < cnt) ? m1 : (cnt - 1))];
  const unsigned short* a0p = tn + (size_t)t0 * H + aq * 8;
  const unsigned short* a1p = tn + (size_t)t1 * H + aq * 8;
  // B staging roles: k-pair = tid&15 (k=2bk), n quad = tid>>4 (n=4bn)
  const int bk = tid & 15, bn = tid >> 4;
  const float* bgp = wg + (size_t)e * H * I_DIM + (size_t)(2 * bk) * I_DIM + nt * 64 + 4 * bn;
  const float* bup = wu + (size_t)e * H * I_DIM + (size_t)(2 * bk) * I_DIM + nt * 64 + 4 * bn;

  f32x4 accg[4][2] = {};
  f32x4 accu[4][2] = {};

  const int lane = tid & 63, wid = tid >> 6;
  const int wm = (wid & 1) * 64, wn = (wid >> 1) * 32;
  const int r16 = lane & 15, q = lane >> 4;

  for (int k0 = 0; k0 < H; k0 += BK) {
    uint4 av0 = *(const uint4*)(a0p + k0);
    uint4 av1 = *(const uint4*)(a1p + k0);
    const float* g0p = bgp + (size_t)k0 * I_DIM;
    float4 g0 = *(const float4*)g0p;
    float4 g1 = *(const float4*)(g0p + I_DIM);
    const float* u0p = bup + (size_t)k0 * I_DIM;
    float4 u0 = *(const float4*)u0p;
    float4 u1 = *(const float4*)(u0p + I_DIM);
    __syncthreads();                    // prev compute done before overwrite
    *(uint4*)&At[ar * LDK + aq * 8] = av0;
    *(uint4*)&At[(ar + 64) * LDK + aq * 8] = av1;
#pragma unroll
    for (int j = 0; j < 4; j++) {
      unsigned int pg = (unsigned int)f2bf(((const float*)&g0)[j]) |
                        ((unsigned int)f2bf(((const float*)&g1)[j]) << 16);
      *(unsigned int*)&Btg[(4 * bn + j) * LDK + 2 * bk] = pg;
      unsigned int pu = (unsigned int)f2bf(((const float*)&u0)[j]) |
                        ((unsigned int)f2bf(((const float*)&u1)[j]) << 16);
      *(unsigned int*)&Btu[(4 * bn + j) * LDK + 2 * bk] = pu;
    }
    __syncthreads();
    s16x8 af[4], bgf[2], buf2[2];
#pragma unroll
    for (int i = 0; i < 4; i++)
      af[i] = *(const s16x8*)&At[(wm + i * 16 + r16) * LDK + q * 8];
#pragma unroll
    for (int j = 0; j < 2; j++) {
      bgf[j] = *(const s16x8*)&Btg[(wn + j * 16 + r16) * LDK + q * 8];
      buf2[j] = *(const s16x8*)&Btu[(wn + j * 16 + r16) * LDK + q * 8];
    }
#pragma unroll
    for (int i = 0; i < 4; i++)
#pragma unroll
      for (int j = 0; j < 2; j++) {
        accg[i][j] = mfma16(af[i], bgf[j], accg[i][j]);
        accu[i][j] = mfma16(af[i], buf2[j], accu[i][j]);
      }
  }

  // epilogue: h = silu(g)*u, bf16 -> hbuf[off+m][nt*64 + wn + j*16 + r16]
#pragma unroll
  for (int i = 0; i < 4; i++) {
#pragma unroll
    for (int rr = 0; rr < 4; rr++) {
      int m = mt * BM + wm + i * 16 + q * 4 + rr;
      if (m < cnt) {
        unsigned short* hp = hbuf + (size_t)(off + m) * I_DIM + nt * 64 + wn + r16;
#pragma unroll
        for (int j = 0; j < 2; j++) {
          float g = accg[i][j][rr], u = accu[i][j][rr];
          float hval = (g / (1.0f + __expf(-g))) * u;
          hp[j * 16] = f2bf(hval);
        }
      }
    }
  }
}

// ---------------- K3: grouped GEMM down, scaled atomicAdd into out ----------------
// BN = 128 here. grid = NE * MT * (H/128), mt fastest
__global__ __launch_bounds__(256) void k_down(
    const unsigned short* __restrict__ hbuf, const float* __restrict__ wd,
    const int* __restrict__ counts, const int* __restrict__ tok,
    const float* __restrict__ wgt, float* __restrict__ out)
{
  __shared__ unsigned short At[BM * LDK];
  __shared__ unsigned short Bt[128 * LDK];

  const int bid = blockIdx.x;
  const int e = bid / (MT * (H / 128));
  const int rem = bid % (MT * (H / 128));
  const int nt = rem >> 4;   // 0..15
  const int mt = rem & 15;
  const int cnt = counts[e];
  if (mt * BM >= cnt) return;
  int off = 0;
#pragma unroll
  for (int i = 0; i < NE; i++) off += (i < e) ? counts[i] : 0;

  const int tid = threadIdx.x;
  const int ar = tid >> 2, aq = tid & 3;
  const int m0 = mt * BM + ar, m1 = m0 + 64;
  const unsigned short* a0p =
      hbuf + (size_t)(off + ((m0 < cnt) ? m0 : (cnt - 1))) * I_DIM + aq * 8;
  const unsigned short* a1p =
      hbuf + (size_t)(off + ((m1 < cnt) ? m1 : (cnt - 1))) * I_DIM + aq * 8;
  const int bk = tid & 15, bn = tid >> 4;
  const float* bp = wd + (size_t)e * I_DIM * H + (size_t)(2 * bk) * H + nt * 128 + 4 * bn;

  f32x4 acc[4][4] = {};

  const int lane = tid & 63, wid = tid >> 6;
  const int wm = (wid & 1) * 64, wn = (wid >> 1) * 64;
  const int r16 = lane & 15, q = lane >> 4;

  for (int k0 = 0; k0 < I_DIM; k0 += BK) {
    uint4 av0 = *(const uint4*)(a0p + k0);
    uint4 av1 = *(const uint4*)(a1p + k0);
    const float* b0 = bp + (size_t)k0 * H;
    float4 d00 = *(const float4*)(b0);
    float4 d01 = *(const float4*)(b0 + H);
    float4 d10 = *(const float4*)(b0 + 64);
    float4 d11 = *(const float4*)(b0 + H + 64);
    __syncthreads();
    *(uint4*)&At[ar * LDK + aq * 8] = av0;
    *(uint4*)&At[(ar + 64) * LDK + aq * 8] = av1;
#pragma unroll
    for (int j = 0; j < 4; j++) {
      unsigned int p0 = (unsigned int)f2bf(((const float*)&d00)[j]) |
                        ((unsigned int)f2bf(((const float*)&d01)[j]) << 16);
      *(unsigned int*)&Bt[(4 * bn + j) * LDK + 2 * bk] = p0;
      unsigned int p1 = (unsigned int)f2bf(((const float*)&d10)[j]) |
                        ((unsigned int)f2bf(((const float*)&d11)[j]) << 16);
      *(unsigned int*)&Bt[(64 + 4 * bn + j) * LDK + 2 * bk] = p1;
    }
    __syncthreads();
    s16x8 af[4], bf[4];
#pragma unroll
    for (int i = 0; i < 4; i++)
      af[i] = *(const s16x8*)&At[(wm + i * 16 + r16) * LDK + q * 8];
#pragma unroll
    for (int j = 0; j < 4; j++)
      bf[j] = *(const s16x8*)&Bt[(wn + j * 16 + r16) * LDK + q * 8];
#pragma unroll
    for (int i = 0; i < 4; i++)
#pragma unroll
      for (int j = 0; j < 4; j++)
        acc[i][j] = mfma16(af[i], bf[j], acc[i][j]);
  }

#pragma unroll
  for (int i = 0; i < 4; i++) {
#pragma unroll
    for (int rr = 0; rr < 4; rr++) {
      int m = mt * BM + wm + i * 16 + q * 4 + rr;
      if (m < cnt) {
        int tkn = tok[e * T_TOK + m];
        float w = wgt[e * T_TOK + m];
        float* op = out + (size_t)tkn * H + nt * 128 + wn + r16;
#pragma unroll
        for (int j = 0; j < 4; j++)
          atomicAdd(&op[j * 16], w * acc[i][j][rr]);
      }
    }
  }
}

// ---------------- launch ----------------
extern "C" void kernel_launch(void* const* d_in, const int* in_sizes, int n_in,
                              void* d_out, int out_size, void* d_ws, size_t ws_size,
                              hipStream_t stream) {
  const float* x  = (const float*)d_in[0];
  const float* nw = (const float*)d_in[1];
  const float* rw = (const float*)d_in[2];
  const float* wg = (const float*)d_in[3];
  const float* wu = (const float*)d_in[4];
  const float* wd = (const float*)d_in[5];
  float* out = (float*)d_out;

  char* ws = (char*)d_ws;
  unsigned short* tn   = (unsigned short*)(ws);                 // 8 MiB  [T][H] bf16
  int* counts          = (int*)(ws + 8388608);                  // 32 B
  int* tok             = (int*)(ws + 8388608 + 256);            // 64 KiB [E][T]
  float* wgt           = (float*)(ws + 8388608 + 256 + 65536);  // 64 KiB [E][T]
  unsigned short* hbuf = (unsigned short*)(ws + 8388608 + 256 + 131072); // 32 MiB [4096][I] bf16

  hipMemsetAsync(counts, 0, 32, stream);
  hipMemsetAsync(out, 0, (size_t)out_size * sizeof(float), stream);
  k_norm_router<<<T_TOK, 256, 0, stream>>>(x, nw, rw, tn, counts, tok, wgt);
  k_gate_up<<<NE * MT * (I_DIM / 64), 256, 0, stream>>>(tn, wg, wu, counts, tok, hbuf);
  k_down<<<NE * MT * (H / 128), 256, 0, stream>>>(hbuf, wd, counts, tok, wgt, out);
}

// Round 2
// 1228.108 us; speedup vs baseline: 1.9527x; 1.9527x over previous
//
#include <hip/hip_runtime.h>

#define H 2048
#define I_DIM 4096
#define NE 8
#define T_TOK 2048

// ---- fallback (round-1) tile params ----
#define BM 128
#define BK 32
#define LDK 40
#define MT 16

typedef float f32x4 __attribute__((ext_vector_type(4)));
typedef short s16x8 __attribute__((ext_vector_type(8)));

__device__ __forceinline__ unsigned short f2bf(float f) {
  unsigned int u = __builtin_bit_cast(unsigned int, f);
  u += 0x7FFFu + ((u >> 16) & 1u);   // RNE
  return (unsigned short)(u >> 16);
}
__device__ __forceinline__ float bf2f(unsigned short s) {
  unsigned int u = ((unsigned int)s) << 16;
  return __builtin_bit_cast(float, u);
}
__device__ __forceinline__ f32x4 mfma16(s16x8 a, s16x8 b, f32x4 c) {
  return __builtin_amdgcn_mfma_f32_16x16x32_bf16(a, b, c, 0, 0, 0);
}
// async global->LDS, 16B per lane; lds dest = wave-uniform base + lane*16
__device__ __forceinline__ void cp16(const void* g, void* l) {
  __builtin_amdgcn_global_load_lds(
      (const __attribute__((address_space(1))) void*)g,
      (__attribute__((address_space(3))) void*)l, 16, 0, 0);
}

// ---------------- K1: RMSNorm + router + top-2 + expert list build ----------------
__global__ __launch_bounds__(256) void k_norm_router(
    const float* __restrict__ x, const float* __restrict__ nw,
    const float* __restrict__ rw, unsigned short* __restrict__ tn,
    int* __restrict__ counts, int* __restrict__ tok, float* __restrict__ wgt)
{
  __shared__ float s_ssq[4];
  __shared__ float s_l[32];
  const int t = blockIdx.x, tid = threadIdx.x;
  const int wid = tid >> 6, lane = tid & 63;

  const float* xr = x + (size_t)t * H + tid * 8;
  float4 v0 = *(const float4*)xr;
  float4 v1 = *(const float4*)(xr + 4);
  float xv[8] = {v0.x, v0.y, v0.z, v0.w, v1.x, v1.y, v1.z, v1.w};

  float ssq = 0.f;
#pragma unroll
  for (int j = 0; j < 8; j++) ssq += xv[j] * xv[j];
#pragma unroll
  for (int o = 32; o > 0; o >>= 1) ssq += __shfl_down(ssq, o);
  if (lane == 0) s_ssq[wid] = ssq;
  __syncthreads();
  const float scale =
      rsqrtf((s_ssq[0] + s_ssq[1] + s_ssq[2] + s_ssq[3]) * (1.0f / H) + 1e-6f);

  const float* nwp = nw + tid * 8;
  float4 w0 = *(const float4*)nwp;
  float4 w1 = *(const float4*)(nwp + 4);
  float wv[8] = {w0.x, w0.y, w0.z, w0.w, w1.x, w1.y, w1.z, w1.w};

  float tv[8];
  union { unsigned short us[8]; uint4 v; } pk;
#pragma unroll
  for (int j = 0; j < 8; j++) {
    tv[j] = xv[j] * scale * wv[j];
    pk.us[j] = f2bf(tv[j]);
  }
  *(uint4*)(tn + (size_t)t * H + tid * 8) = pk.v;

  float l[8] = {0, 0, 0, 0, 0, 0, 0, 0};
  const float* rwp = rw + (size_t)(tid * 8) * NE;
#pragma unroll
  for (int j = 0; j < 8; j++) {
#pragma unroll
    for (int e2 = 0; e2 < 8; e2++) l[e2] += tv[j] * rwp[j * NE + e2];
  }
#pragma unroll
  for (int e2 = 0; e2 < 8; e2++) {
#pragma unroll
    for (int o = 32; o > 0; o >>= 1) l[e2] += __shfl_down(l[e2], o);
  }
  if (lane == 0) {
#pragma unroll
    for (int e2 = 0; e2 < 8; e2++) s_l[wid * 8 + e2] = l[e2];
  }
  __syncthreads();
  if (tid == 0) {
    float tot[8];
#pragma unroll
    for (int e2 = 0; e2 < 8; e2++)
      tot[e2] = s_l[e2] + s_l[8 + e2] + s_l[16 + e2] + s_l[24 + e2];
    int b0 = 0; float m0 = tot[0];
#pragma unroll
    for (int e2 = 1; e2 < 8; e2++) if (tot[e2] > m0) { m0 = tot[e2]; b0 = e2; }
    int b1 = -1; float m1 = -3.4e38f;
#pragma unroll
    for (int e2 = 0; e2 < 8; e2++)
      if (e2 != b0 && tot[e2] > m1) { m1 = tot[e2]; b1 = e2; }
    float wa = 1.0f / (1.0f + expf(m1 - m0));
    float wb = 1.0f - wa;
    int p0 = atomicAdd(&counts[b0], 1);
    tok[b0 * T_TOK + p0] = t; wgt[b0 * T_TOK + p0] = wa;
    int p1 = atomicAdd(&counts[b1], 1);
    tok[b1 * T_TOK + p1] = t; wgt[b1 * T_TOK + p1] = wb;
  }
}

// =======================================================================
// FAST PATH (needs ~248 MB ws)
// Packed chunk format: 8 KB = [n=0..127][kq=0..3] cells of 16B (8 bf16 along k),
// cell (n,kq) at slot s = n*4 + (kq ^ ((n>>1)&3))  (XOR swizzle: <=2-way LDS conflicts)
// =======================================================================

__device__ __forceinline__ int tile_index(const int* counts, int e, int mt, int* cnt_out) {
  int idx = 0, cnt = 0;
#pragma unroll
  for (int i = 0; i < NE; i++) {
    int c = counts[i];
    if (i < e) idx += (c + 127) >> 7;
    if (i == e) cnt = c;
  }
  *cnt_out = cnt;
  return idx + mt;
}

// ---- pack fp32 weights [e][K_tot][N_tot] -> bf16 panels [e*NT+nt][kt][slot] ----
__global__ __launch_bounds__(256) void k_pack_w(
    const float* __restrict__ src, char* __restrict__ dst, int KT, int NT)
{
  __shared__ __align__(16) unsigned short Lt[128 * 40];  // [n(0..127)][k(0..31)], stride 40
  const int tid = threadIdx.x;
  int bid = blockIdx.x;
  const int nt = bid % NT; bid /= NT;
  const int kt = bid % KT; const int e = bid / KT;
  const int K_tot = KT * 32, N_tot = NT * 128;

  // load 32 k-rows x 128 n-cols fp32; thread: row k=tid>>3, cols (tid&7)*16..+15
  const int k = tid >> 3, c0 = (tid & 7) * 16;
  const float* sp = src + ((size_t)e * K_tot + (size_t)kt * 32 + k) * N_tot + (size_t)nt * 128 + c0;
  float4 f0 = *(const float4*)(sp);
  float4 f1 = *(const float4*)(sp + 4);
  float4 f2 = *(const float4*)(sp + 8);
  float4 f3 = *(const float4*)(sp + 12);
  float fv[16] = {f0.x,f0.y,f0.z,f0.w, f1.x,f1.y,f1.z,f1.w,
                  f2.x,f2.y,f2.z,f2.w, f3.x,f3.y,f3.z,f3.w};
#pragma unroll
  for (int j = 0; j < 16; j++) Lt[(c0 + j) * 40 + k] = f2bf(fv[j]);
  __syncthreads();

  char* dp = dst + (((size_t)(e * NT + nt)) * KT + kt) * 8192;
#pragma unroll
  for (int hh = 0; hh < 2; hh++) {
    int s = tid + hh * 256;
    int n = s >> 2;
    int kq = (s & 3) ^ ((n >> 1) & 3);
    uint4 v = *(const uint4*)&Lt[n * 40 + kq * 8];
    *(uint4*)(dp + (size_t)s * 16) = v;
  }
}

// ---- pack gathered A (tn rows by expert order) -> Apack tiles ----
__global__ __launch_bounds__(256) void k_pack_a(
    const unsigned short* __restrict__ tn, const int* __restrict__ counts,
    const int* __restrict__ tok, char* __restrict__ Apack)
{
  const int bid = blockIdx.x;
  const int e = bid >> 4, mt = bid & 15;
  int cnt; const int tix = tile_index(counts, e, mt, &cnt);
  if (mt * 128 >= cnt) return;
  const int tid = threadIdx.x;

  // two cells per kt: s = tid, tid+256
  int s0 = tid, s1 = tid + 256;
  int m0 = s0 >> 2, m1 = s1 >> 2;
  int kq0 = (s0 & 3) ^ ((m0 >> 1) & 3);
  int kq1 = (s1 & 3) ^ ((m1 >> 1) & 3);
  int r0 = mt * 128 + m0, r1 = mt * 128 + m1;
  int t0 = tok[e * T_TOK + ((r0 < cnt) ? r0 : (cnt - 1))];
  int t1 = tok[e * T_TOK + ((r1 < cnt) ? r1 : (cnt - 1))];
  const unsigned short* sp0 = tn + (size_t)t0 * H + kq0 * 8;
  const unsigned short* sp1 = tn + (size_t)t1 * H + kq1 * 8;
  char* dp = Apack + (size_t)tix * 64 * 8192;
  for (int kt = 0; kt < 64; ++kt) {
    uint4 v0 = *(const uint4*)(sp0 + kt * 32);
    uint4 v1 = *(const uint4*)(sp1 + kt * 32);
    *(uint4*)(dp + (size_t)kt * 8192 + (size_t)s0 * 16) = v0;
    *(uint4*)(dp + (size_t)kt * 8192 + (size_t)s1 * 16) = v1;
  }
}

// ---- shared GEMM main loop: 128x128 tile, BK=32, global_load_lds staging ----
#define GEMM_PROLOG(NPANEL_BITS, NT_MASK)                                   \
  const int tid = threadIdx.x, lane = tid & 63, wid = tid >> 6;             \
  const int r16 = lane & 15, q = lane >> 4;                                 \
  const int wm = (wid & 1) * 64, wn = (wid >> 1) * 64;                      \
  const int offA = (wm + r16) * 64 + (q ^ ((r16 >> 1) & 3)) * 16;           \
  const int offB = (wn + r16) * 64 + (q ^ ((r16 >> 1) & 3)) * 16;

#define GEMM_LOOP(KT_N)                                                     \
  {                                                                         \
    const char* gA = Ac + wid * 2048 + lane * 16;                           \
    const char* gB = Bc + wid * 2048 + lane * 16;                           \
    char* lA = smem + wid * 2048;                                           \
    char* lB = smem + 8192 + wid * 2048;                                    \
    for (int kt = 0; kt < (KT_N); ++kt) {                                   \
      __syncthreads();                                                      \
      cp16(gA, lA); cp16(gA + 1024, lA + 1024);                             \
      cp16(gB, lB); cp16(gB + 1024, lB + 1024);                             \
      gA += 8192; gB += 8192;                                               \
      __syncthreads();                                                      \
      s16x8 af[4], bf[4];                                                   \
      _Pragma("unroll")                                                     \
      for (int i = 0; i < 4; i++) af[i] = *(const s16x8*)(smem + offA + i * 1024); \
      _Pragma("unroll")                                                     \
      for (int j = 0; j < 4; j++) bf[j] = *(const s16x8*)(smem + 8192 + offB + j * 1024); \
      _Pragma("unroll")                                                     \
      for (int i = 0; i < 4; i++)                                           \
        _Pragma("unroll")                                                   \
        for (int j = 0; j < 4; j++) acc[i][j] = mfma16(af[i], bf[j], acc[i][j]); \
    }                                                                       \
  }

// ---- gate GEMM: g = A * Wg -> gbuf (per-block flat frag layout) ----
__global__ __launch_bounds__(256) void k_gemm_gate(
    const char* __restrict__ Apack, const char* __restrict__ Wbuf,
    const int* __restrict__ counts, char* __restrict__ gbuf)
{
  __shared__ __align__(16) char smem[16384];
  const int bid = blockIdx.x;
  const int panel = bid & 255;           // e*32+nt; bid = mt*256+panel (XCD swizzle)
  const int mt = bid >> 8;
  const int e = panel >> 5, nt = panel & 31;
  int cnt; const int tix = tile_index(counts, e, mt, &cnt);
  if (mt * 128 >= cnt) return;
  const char* Ac = Apack + (size_t)tix * 64 * 8192;
  const char* Bc = Wbuf + (size_t)panel * 64 * 8192;
  f32x4 acc[4][4] = {};
  GEMM_PROLOG(8, 31)
  GEMM_LOOP(64)
  char* gb = gbuf + ((size_t)tix * 32 + nt) * 32768 + (size_t)tid * 128;
#pragma unroll
  for (int i = 0; i < 4; i++)
#pragma unroll
    for (int j = 0; j < 4; j++) {
      uint2 p;
      p.x = (unsigned int)f2bf(acc[i][j][0]) | ((unsigned int)f2bf(acc[i][j][1]) << 16);
      p.y = (unsigned int)f2bf(acc[i][j][2]) | ((unsigned int)f2bf(acc[i][j][3]) << 16);
      *(uint2*)(gb + (i * 4 + j) * 8) = p;
    }
}

// ---- up GEMM + silu(g)*u fused -> Hpack (packed layout for down GEMM) ----
__global__ __launch_bounds__(256) void k_gemm_up(
    const char* __restrict__ Apack, const char* __restrict__ Wbuf,
    const int* __restrict__ counts, const char* __restrict__ gbuf,
    char* __restrict__ Hpack)
{
  __shared__ __align__(16) char smem[128 * 136 * 2];  // loop uses first 16 KB
  const int bid = blockIdx.x;
  const int panel = bid & 255;
  const int mt = bid >> 8;
  const int e = panel >> 5, nt = panel & 31;
  int cnt; const int tix = tile_index(counts, e, mt, &cnt);
  if (mt * 128 >= cnt) return;
  const char* Ac = Apack + (size_t)tix * 64 * 8192;
  const char* Bc = Wbuf + (size_t)panel * 64 * 8192;
  f32x4 acc[4][4] = {};
  GEMM_PROLOG(8, 31)
  GEMM_LOOP(64)

  const char* gb = gbuf + ((size_t)tix * 32 + nt) * 32768 + (size_t)tid * 128;
  uint2 gv[16];
#pragma unroll
  for (int f = 0; f < 16; f++) gv[f] = *(const uint2*)(gb + f * 8);

  __syncthreads();  // main-loop LDS reads done; reuse smem as hLDS [128][136]
  unsigned short* hL = (unsigned short*)smem;
#pragma unroll
  for (int i = 0; i < 4; i++)
#pragma unroll
    for (int j = 0; j < 4; j++) {
      uint2 g2 = gv[i * 4 + j];
#pragma unroll
      for (int rr = 0; rr < 4; rr++) {
        unsigned short gu = (rr < 2) ? (unsigned short)(g2.x >> (rr * 16))
                                     : (unsigned short)(g2.y >> ((rr - 2) * 16));
        float g = bf2f(gu);
        float u = acc[i][j][rr];
        float h = (g / (1.0f + __expf(-g))) * u;
        hL[(wm + i * 16 + q * 4 + rr) * 136 + wn + j * 16 + r16] = f2bf(h);
      }
    }
  __syncthreads();
  char* Hdst = Hpack + ((size_t)tix * 128 + nt * 4) * 8192;
#pragma unroll
  for (int c = 0; c < 8; c++) {
    int cid = tid + c * 256;
    int ktl = cid >> 9, s = cid & 511;
    int n = s >> 2, kq = (s & 3) ^ ((n >> 1) & 3);
    uint4 v = *(const uint4*)&hL[n * 136 + ktl * 32 + kq * 8];
    *(uint4*)(Hdst + (size_t)ktl * 8192 + (size_t)s * 16) = v;
  }
}

// ---- down GEMM: out += C[t,e] * (h * Wd) via atomicAdd ----
__global__ __launch_bounds__(256) void k_gemm_down(
    const char* __restrict__ Hpack, const char* __restrict__ Wbuf,
    const int* __restrict__ counts, const int* __restrict__ tok,
    const float* __restrict__ wgt, float* __restrict__ out)
{
  __shared__ __align__(16) char smem[16384];
  const int bid = blockIdx.x;
  const int panel = bid & 127;           // e*16+nt; bid = mt*128+panel
  const int mt = bid >> 7;
  const int e = panel >> 4, nt = panel & 15;
  int cnt; const int tix = tile_index(counts, e, mt, &cnt);
  if (mt * 128 >= cnt) return;
  const char* Ac = Hpack + (size_t)tix * 128 * 8192;
  const char* Bc = Wbuf + (size_t)panel * 128 * 8192;
  f32x4 acc[4][4] = {};
  GEMM_PROLOG(7, 15)
  GEMM_LOOP(128)
#pragma unroll
  for (int i = 0; i < 4; i++) {
#pragma unroll
    for (int rr = 0; rr < 4; rr++) {
      int m = mt * 128 + wm + i * 16 + q * 4 + rr;
      if (m < cnt) {
        int tkn = tok[e * T_TOK + m];
        float w = wgt[e * T_TOK + m];
        float* op = out + (size_t)tkn * H + nt * 128 + wn + r16;
#pragma unroll
        for (int j = 0; j < 4; j++)
          atomicAdd(&op[j * 16], w * acc[i][j][rr]);
      }
    }
  }
}

// =======================================================================
// FALLBACK PATH (round-1 kernels, ~40 MB ws)
// =======================================================================
__global__ __launch_bounds__(256) void fb_gate_up(
    const unsigned short* __restrict__ tn,
    const float* __restrict__ wg, const float* __restrict__ wu,
    const int* __restrict__ counts, const int* __restrict__ tok,
    unsigned short* __restrict__ hbuf)
{
  __shared__ unsigned short At[BM * LDK];
  __shared__ unsigned short Btg[64 * LDK];
  __shared__ unsigned short Btu[64 * LDK];
  const int bid = blockIdx.x;
  const int e = bid / (MT * (I_DIM / 64));
  const int rem = bid % (MT * (I_DIM / 64));
  const int nt = rem >> 4;
  const int mt = rem & 15;
  const int cnt = counts[e];
  if (mt * BM >= cnt) return;
  int off = 0;
#pragma unroll
  for (int i = 0; i < NE; i++) off += (i < e) ? counts[i] : 0;
  const int tid = threadIdx.x;
  const int ar = tid >> 2, aq = tid & 3;
  const int m0 = mt * BM + ar, m1 = m0 + 64;
  const int t0 = tok[e * T_TOK + ((m0 < cnt) ? m0 : (cnt - 1))];
  const int t1 = tok[e * T_TOK + ((m1 < cnt) ? m1 : (cnt - 1))];
  const unsigned short* a0p = tn + (size_t)t0 * H + aq * 8;
  const unsigned short* a1p = tn + (size_t)t1 * H + aq * 8;
  const int bk = tid & 15, bn = tid >> 4;
  const float* bgp = wg + (size_t)e * H * I_DIM + (size_t)(2 * bk) * I_DIM + nt * 64 + 4 * bn;
  const float* bup = wu + (size_t)e * H * I_DIM + (size_t)(2 * bk) * I_DIM + nt * 64 + 4 * bn;
  f32x4 accg[4][2] = {};
  f32x4 accu[4][2] = {};
  const int lane = tid & 63, wid = tid >> 6;
  const int wm = (wid & 1) * 64, wn = (wid >> 1) * 32;
  const int r16 = lane & 15, q = lane >> 4;
  for (int k0 = 0; k0 < H; k0 += BK) {
    uint4 av0 = *(const uint4*)(a0p + k0);
    uint4 av1 = *(const uint4*)(a1p + k0);
    const float* g0p = bgp + (size_t)k0 * I_DIM;
    float4 g0 = *(const float4*)g0p;
    float4 g1 = *(const float4*)(g0p + I_DIM);
    const float* u0p = bup + (size_t)k0 * I_DIM;
    float4 u0 = *(const float4*)u0p;
    float4 u1 = *(const float4*)(u0p + I_DIM);
    __syncthreads();
    *(uint4*)&At[ar * LDK + aq * 8] = av0;
    *(uint4*)&At[(ar + 64) * LDK + aq * 8] = av1;
#pragma unroll
    for (int j = 0; j < 4; j++) {
      unsigned int pg = (unsigned int)f2bf(((const float*)&g0)[j]) |
                        ((unsigned int)f2bf(((const float*)&g1)[j]) << 16);
      *(unsigned int*)&Btg[(4 * bn + j) * LDK + 2 * bk] = pg;
      unsigned int pu = (unsigned int)f2bf(((const float*)&u0)[j]) |
                        ((unsigned int)f2bf(((const float*)&u1)[j]) << 16);
      *(unsigned int*)&Btu[(4 * bn + j) * LDK + 2 * bk] = pu;
    }
    __syncthreads();
    s16x8 af[4], bgf[2], buf2[2];
#pragma unroll
    for (int i = 0; i < 4; i++)
      af[i] = *(const s16x8*)&At[(wm + i * 16 + r16) * LDK + q * 8];
#pragma unroll
    for (int j = 0; j < 2; j++) {
      bgf[j] = *(const s16x8*)&Btg[(wn + j * 16 + r16) * LDK + q * 8];
      buf2[j] = *(const s16x8*)&Btu[(wn + j * 16 + r16) * LDK + q * 8];
    }
#pragma unroll
    for (int i = 0; i < 4; i++)
#pragma unroll
      for (int j = 0; j < 2; j++) {
        accg[i][j] = mfma16(af[i], bgf[j], accg[i][j]);
        accu[i][j] = mfma16(af[i], buf2[j], accu[i][j]);
      }
  }
#pragma unroll
  for (int i = 0; i < 4; i++) {
#pragma unroll
    for (int rr = 0; rr < 4; rr++) {
      int m = mt * BM + wm + i * 16 + q * 4 + rr;
      if (m < cnt) {
        unsigned short* hp = hbuf + (size_t)(off + m) * I_DIM + nt * 64 + wn + r16;
#pragma unroll
        for (int j = 0; j < 2; j++) {
          float g = accg[i][j][rr], u = accu[i][j][rr];
          float hval = (g / (1.0f + __expf(-g))) * u;
          hp[j * 16] = f2bf(hval);
        }
      }
    }
  }
}

__global__ __launch_bounds__(256) void fb_down(
    const unsigned short* __restrict__ hbuf, const float* __restrict__ wd,
    const int* __restrict__ counts, const int* __restrict__ tok,
    const float* __restrict__ wgt, float* __restrict__ out)
{
  __shared__ unsigned short At[BM * LDK];
  __shared__ unsigned short Bt[128 * LDK];
  const int bid = blockIdx.x;
  const int e = bid / (MT * (H / 128));
  const int rem = bid % (MT * (H / 128));
  const int nt = rem >> 4;
  const int mt = rem & 15;
  const int cnt = counts[e];
  if (mt * BM >= cnt) return;
  int off = 0;
#pragma unroll
  for (int i = 0; i < NE; i++) off += (i < e) ? counts[i] : 0;
  const int tid = threadIdx.x;
  const int ar = tid >> 2, aq = tid & 3;
  const int m0 = mt * BM + ar, m1 = m0 + 64;
  const unsigned short* a0p =
      hbuf + (size_t)(off + ((m0 < cnt) ? m0 : (cnt - 1))) * I_DIM + aq * 8;
  const unsigned short* a1p =
      hbuf + (size_t)(off + ((m1 < cnt) ? m1 : (cnt - 1))) * I_DIM + aq * 8;
  const int bk = tid & 15, bn = tid >> 4;
  const float* bp = wd + (size_t)e * I_DIM * H + (size_t)(2 * bk) * H + nt * 128 + 4 * bn;
  f32x4 acc[4][4] = {};
  const int lane = tid & 63, wid = tid >> 6;
  const int wm = (wid & 1) * 64, wn = (wid >> 1) * 64;
  const int r16 = lane & 15, q = lane >> 4;
  for (int k0 = 0; k0 < I_DIM; k0 += BK) {
    uint4 av0 = *(const uint4*)(a0p + k0);
    uint4 av1 = *(const uint4*)(a1p + k0);
    const float* b0 = bp + (size_t)k0 * H;
    float4 d00 = *(const float4*)(b0);
    float4 d01 = *(const float4*)(b0 + H);
    float4 d10 = *(const float4*)(b0 + 64);
    float4 d11 = *(const float4*)(b0 + H + 64);
    __syncthreads();
    *(uint4*)&At[ar * LDK + aq * 8] = av0;
    *(uint4*)&At[(ar + 64) * LDK + aq * 8] = av1;
#pragma unroll
    for (int j = 0; j < 4; j++) {
      unsigned int p0 = (unsigned int)f2bf(((const float*)&d00)[j]) |
                        ((unsigned int)f2bf(((const float*)&d01)[j]) << 16);
      *(unsigned int*)&Bt[(4 * bn + j) * LDK + 2 * bk] = p0;
      unsigned int p1 = (unsigned int)f2bf(((const float*)&d10)[j]) |
                        ((unsigned int)f2bf(((const float*)&d11)[j]) << 16);
      *(unsigned int*)&Bt[(64 + 4 * bn + j) * LDK + 2 * bk] = p1;
    }
    __syncthreads();
    s16x8 af[4], bf[4];
#pragma unroll
    for (int i = 0; i < 4; i++)
      af[i] = *(const s16x8*)&At[(wm + i * 16 + r16) * LDK + q * 8];
#pragma unroll
    for (int j = 0; j < 4; j++)
      bf[j] = *(const s16x8*)&Bt[(wn + j * 16 + r16) * LDK + q * 8];
#pragma unroll
    for (int i = 0; i < 4; i++)
#pragma unroll
      for (int j = 0; j < 4; j++)
        acc[i][j] = mfma16(af[i], bf[j], acc[i][j]);
  }
#pragma unroll
  for (int i = 0; i < 4; i++) {
#pragma unroll
    for (int rr = 0; rr < 4; rr++) {
      int m = mt * BM + wm + i * 16 + q * 4 + rr;
      if (m < cnt) {
        int tkn = tok[e * T_TOK + m];
        float w = wgt[e * T_TOK + m];
        float* op = out + (size_t)tkn * H + nt * 128 + wn + r16;
#pragma unroll
        for (int j = 0; j < 4; j++)
          atomicAdd(&op[j * 16], w * acc[i][j][rr]);
      }
    }
  }
}

// ---------------- launch ----------------
extern "C" void kernel_launch(void* const* d_in, const int* in_sizes, int n_in,
                              void* d_out, int out_size, void* d_ws, size_t ws_size,
                              hipStream_t stream) {
  const float* x  = (const float*)d_in[0];
  const float* nw = (const float*)d_in[1];
  const float* rw = (const float*)d_in[2];
  const float* wg = (const float*)d_in[3];
  const float* wu = (const float*)d_in[4];
  const float* wd = (const float*)d_in[5];
  float* out = (float*)d_out;
  char* ws = (char*)d_ws;

  // ws layout (fast path):
  const size_t o_tn    = 0;                       // 8,388,608
  const size_t o_cnt   = 8388608;                 // 256
  const size_t o_tok   = 8388864;                 // 65,536
  const size_t o_wgt   = 8454400;                 // 65,536
  const size_t o_apack = 8519936;                 // 20,971,520
  const size_t o_gbuf  = 29491456;                // 41,943,040
  const size_t o_hpack = 71434496;                // 41,943,040
  const size_t o_wbuf  = 113377536;               // 134,217,728
  const size_t need    = 247595264;

  unsigned short* tn = (unsigned short*)(ws + o_tn);
  int* counts        = (int*)(ws + o_cnt);
  int* tok           = (int*)(ws + o_tok);
  float* wgt         = (float*)(ws + o_wgt);

  hipMemsetAsync(counts, 0, 32, stream);
  hipMemsetAsync(out, 0, (size_t)out_size * sizeof(float), stream);
  k_norm_router<<<T_TOK, 256, 0, stream>>>(x, nw, rw, tn, counts, tok, wgt);

  if (ws_size >= need) {
    char* Apack = ws + o_apack;
    char* gbuf  = ws + o_gbuf;
    char* Hpack = ws + o_hpack;
    char* Wbuf  = ws + o_wbuf;
    // A pack (gather tokens into tiled-swizzled bf16 panels)
    k_pack_a<<<NE * 16, 256, 0, stream>>>(tn, counts, tok, Apack);
    // gate: pack Wg then GEMM (Wbuf reused across the three GEMMs; stream order serializes)
    k_pack_w<<<NE * 64 * 32, 256, 0, stream>>>(wg, Wbuf, 64, 32);
    k_gemm_gate<<<16 * 256, 256, 0, stream>>>(Apack, Wbuf, counts, gbuf);
    // up: pack Wu then GEMM+silu fuse -> Hpack
    k_pack_w<<<NE * 64 * 32, 256, 0, stream>>>(wu, Wbuf, 64, 32);
    k_gemm_up<<<16 * 256, 256, 0, stream>>>(Apack, Wbuf, counts, gbuf, Hpack);
    // down: pack Wd then GEMM -> atomic combine
    k_pack_w<<<NE * 128 * 16, 256, 0, stream>>>(wd, Wbuf, 128, 16);
    k_gemm_down<<<16 * 128, 256, 0, stream>>>(Hpack, Wbuf, counts, tok, wgt, out);
  } else {
    // fallback: round-1 path (~40 MB ws)
    unsigned short* hbuf = (unsigned short*)(ws + 8388608 + 256 + 131072);
    fb_gate_up<<<NE * MT * (I_DIM / 64), 256, 0, stream>>>(tn, wg, wu, counts, tok, hbuf);
    fb_down<<<NE * MT * (H / 128), 256, 0, stream>>>(hbuf, wd, counts, tok, wgt, out);
  }
}